// Round 9
// baseline (578.837 us; speedup 1.0000x reference)
//
#include <hip/hip_runtime.h>
#include <hip/hip_bf16.h>

typedef unsigned short u16;
typedef unsigned int   u32;
typedef __attribute__((ext_vector_type(8))) short short8;
typedef __attribute__((ext_vector_type(4))) float floatx4;

__device__ __forceinline__ float bits2f(u32 v){ float f; __builtin_memcpy(&f, &v, 4); return f; }
__device__ __forceinline__ u16 f2bf(float f){
    __hip_bfloat16 h = __float2bfloat16(f);
    u16 u; __builtin_memcpy(&u, &h, 2); return u;
}

// ---------------- f32 -> bf16 conversion (x into hbuf) ----------------

__global__ __launch_bounds__(256) void cvt_kernel(const float* __restrict__ in,
                                                  u16* __restrict__ out, int total4){
    int i = blockIdx.x * 256 + threadIdx.x;
    if (i >= total4) return;
    float4 v = ((const float4*)in)[i];
    uint2 o;
    o.x = (u32)f2bf(v.x) | ((u32)f2bf(v.y) << 16);
    o.y = (u32)f2bf(v.z) | ((u32)f2bf(v.w) << 16);
    ((uint2*)out)[i] = o;
}

// ---------------- CSR build: bucket hist -> bucket scan -> multisplit bin -> bucket sort ----------------

__global__ __launch_bounds__(256) void bhist_kernel(const int* __restrict__ dst,
                                                    int* __restrict__ gbcnt, int E){
    __shared__ int bc[256];
    const int t = threadIdx.x;
    bc[t] = 0;
    __syncthreads();
    const int tile0 = blockIdx.x * 8192;
    const int cnt = min(8192, E - tile0);
    for (int j = t; j < cnt; j += 256) atomicAdd(&bc[dst[tile0 + j] >> 9], 1);
    __syncthreads();
    if (bc[t] > 0) atomicAdd(&gbcnt[t], bc[t]);
}

__global__ __launch_bounds__(256) void bscan_kernel(const int* __restrict__ gbcnt,
                                                    int* __restrict__ bbase,
                                                    int* __restrict__ bcur, int nbuk){
    __shared__ int ws[4];
    const int t = threadIdx.x, lane = t & 63, wv = t >> 6;
    int v = (t < nbuk) ? gbcnt[t] : 0;
    int s = v;
    for (int off = 1; off < 64; off <<= 1){
        int n = __shfl_up(s, off);
        if (lane >= off) s += n;
    }
    if (lane == 63) ws[wv] = s;
    __syncthreads();
    int woff = 0;
    for (int w = 0; w < wv; ++w) woff += ws[w];
    int excl = s + woff - v;
    if (t < nbuk){ bbase[t] = excl; bcur[t] = excl; }
}

#define BIN_TILE 8192
__global__ __launch_bounds__(256) void bin_kernel(const int* __restrict__ src,
                                                  const int* __restrict__ dst,
                                                  int* __restrict__ bcur,
                                                  u32* __restrict__ pairs, int E, int nbuk){
    __shared__ u32 hcnt[256], hexcl[256], hoff[256];
    __shared__ int gbase[256];
    __shared__ u32 stage[BIN_TILE];
    __shared__ unsigned char bkt[BIN_TILE];
    const int t = threadIdx.x;
    const int tile0 = blockIdx.x * BIN_TILE;
    const int cntE = min(BIN_TILE, E - tile0);

    hcnt[t] = 0;
    __syncthreads();
    for (int j = t; j < cntE; j += 256){
        int d = dst[tile0 + j];
        atomicAdd(&hcnt[d >> 9], 1u);
    }
    __syncthreads();
    if (t < 64){
        u32 a0 = hcnt[4*t], a1 = hcnt[4*t+1], a2 = hcnt[4*t+2], a3 = hcnt[4*t+3];
        u32 lsum = a0 + a1 + a2 + a3;
        u32 s = lsum;
        for (int off = 1; off < 64; off <<= 1){
            u32 n = __shfl_up(s, off);
            if (t >= off) s += n;
        }
        u32 base = s - lsum;
        hexcl[4*t]   = base;
        hexcl[4*t+1] = base + a0;
        hexcl[4*t+2] = base + a0 + a1;
        hexcl[4*t+3] = base + a0 + a1 + a2;
        hoff[4*t]   = base;
        hoff[4*t+1] = base + a0;
        hoff[4*t+2] = base + a0 + a1;
        hoff[4*t+3] = base + a0 + a1 + a2;
    }
    __syncthreads();
    if (t < nbuk && hcnt[t] > 0) gbase[t] = atomicAdd(&bcur[t], (int)hcnt[t]);
    for (int j = t; j < cntE; j += 256){
        int d = dst[tile0 + j];
        int s = src[tile0 + j];
        int b = d >> 9;
        u32 p = atomicAdd(&hoff[b], 1u);
        stage[p] = ((u32)s << 9) | (u32)(d & 511);
        bkt[p] = (unsigned char)b;
    }
    __syncthreads();
    for (int j = t; j < cntE; j += 256){
        int b = bkt[j];
        pairs[gbase[b] + (int)((u32)j - hexcl[b])] = stage[j];
    }
}

__global__ __launch_bounds__(256) void sort2_kernel(const u32* __restrict__ pairs,
                                                    const int* __restrict__ bbase,
                                                    int* __restrict__ indptr,
                                                    float* __restrict__ invdeg,
                                                    int* __restrict__ esrc,
                                                    int M, int E, int nbuk){
    __shared__ int ndeg[512];
    __shared__ int cur[512];
    __shared__ int wsI[4];
    const int b = blockIdx.x;
    const int node0 = b * 512;
    const int lo = bbase[b];
    const int hi = (b + 1 < nbuk) ? bbase[b + 1] : E;
    const int t = threadIdx.x, lane = t & 63, wv = t >> 6;

    ndeg[t] = 0; ndeg[t + 256] = 0;
    __syncthreads();
    for (int i = lo + t; i < hi; i += 256) atomicAdd(&ndeg[pairs[i] & 511], 1);
    __syncthreads();

    const int d0 = ndeg[2*t], d1 = ndeg[2*t + 1];
    const int p = d0 + d1;
    int s = p;
    for (int off = 1; off < 64; off <<= 1){
        int n = __shfl_up(s, off);
        if (lane >= off) s += n;
    }
    if (lane == 63) wsI[wv] = s;
    __syncthreads();
    int woff = 0;
    for (int w = 0; w < wv; ++w) woff += wsI[w];
    const int incl = s + woff;
    const int excl0 = incl - p;
    const int excl1 = excl0 + d0;

    const int n0 = node0 + 2*t, n1 = node0 + 2*t + 1;
    if (n0 < M){
        indptr[n0 + 1] = lo + excl0 + d0;
        invdeg[n0] = 1.0f / (float)max(d0, 1);
        cur[2*t] = lo + excl0;
    }
    if (n1 < M){
        indptr[n1 + 1] = lo + excl1 + d1;
        invdeg[n1] = 1.0f / (float)max(d1, 1);
        cur[2*t + 1] = lo + excl1;
    }
    if (b == 0 && t == 0) indptr[0] = 0;
    __syncthreads();
    for (int i = lo + t; i < hi; i += 256){
        u32 v = pairs[i];
        int pos = atomicAdd(&cur[v & 511], 1);
        esrc[pos] = (int)(v >> 9);
    }
}

// ---------------- degree-balanced node ordering (counting sort by degree, 64 bins) ----------------

__global__ __launch_bounds__(256) void deghist_kernel(const int* __restrict__ indptr,
                                                      int* __restrict__ dh, int M){
    __shared__ int h[64];
    const int t = threadIdx.x;
    if (t < 64) h[t] = 0;
    __syncthreads();
    const int tile0 = blockIdx.x * 8192;
    const int cnt = min(8192, M - tile0);
    for (int j = t; j < cnt; j += 256){
        int d = min(indptr[tile0 + j + 1] - indptr[tile0 + j], 63);
        atomicAdd(&h[d], 1);
    }
    __syncthreads();
    if (t < 64 && h[t] > 0) atomicAdd(&dh[t], h[t]);
}

__global__ void degscan_kernel(const int* __restrict__ dh, int* __restrict__ dcur){
    const int t = threadIdx.x;  // 64 threads = 1 wave
    int v = dh[t];
    int s = v;
    for (int off = 1; off < 64; off <<= 1){
        int n = __shfl_up(s, off);
        if (t >= off) s += n;
    }
    int total = __shfl(s, 63);
    dcur[t] = total - s;   // descending-degree base: sum of counts of bins > t ... (bin t starts after all higher bins)
}

__global__ __launch_bounds__(256) void degplace_kernel(const int* __restrict__ indptr,
                                                       int* __restrict__ dcur,
                                                       int* __restrict__ nodemap, int M){
    __shared__ int h[64], excl[64], off64[64], gb[64];
    __shared__ int stageN[4096];
    __shared__ unsigned char sb[4096];
    const int t = threadIdx.x;
    const int tile0 = blockIdx.x * 4096;
    const int cnt = min(4096, M - tile0);

    if (t < 64) h[t] = 0;
    __syncthreads();
    for (int j = t; j < cnt; j += 256){
        int d = min(indptr[tile0 + j + 1] - indptr[tile0 + j], 63);
        atomicAdd(&h[d], 1);
    }
    __syncthreads();
    if (t < 64){
        int v = h[t];
        int s = v;
        for (int off = 1; off < 64; off <<= 1){
            int n = __shfl_up(s, off);
            if (t >= off) s += n;
        }
        excl[t] = s - v;
        off64[t] = s - v;
    }
    __syncthreads();
    if (t < 64 && h[t] > 0) gb[t] = atomicAdd(&dcur[t], h[t]);
    for (int j = t; j < cnt; j += 256){
        int d = min(indptr[tile0 + j + 1] - indptr[tile0 + j], 63);
        int p = atomicAdd(&off64[d], 1);
        stageN[p] = tile0 + j;
        sb[p] = (unsigned char)d;
    }
    __syncthreads();
    for (int j = t; j < cnt; j += 256){
        int d = sb[j];
        nodemap[gb[d] + j - excl[d]] = stageN[j];
    }
}

// ------- weight packing -------

__global__ void pack_kernel(const float* __restrict__ wself, const float* __restrict__ wneigh,
                            u16* __restrict__ bp, int N){
    int i = blockIdx.x * 256 + threadIdx.x;
    if (i >= N * 256) return;
    int n = i >> 8, k = i & 255;
    float v = (k < 128) ? wself[k * N + n] : wneigh[(k - 128) * N + n];
    bp[i] = f2bf(v);
}

// ---------------- aggregation (degree-balanced via nodemap, optional fused affine+ReLU) -------

template<bool AFF>
__global__ __launch_bounds__(256) void agg_kernel(const u16* __restrict__ h,
                                                  const int* __restrict__ indptr,
                                                  const int* __restrict__ esrc,
                                                  const float* __restrict__ invdeg,
                                                  const float* __restrict__ cs,
                                                  const int* __restrict__ nodemap,
                                                  u16* __restrict__ agg, int M){
    const int wave = threadIdx.x >> 6;
    const int lane = threadIdx.x & 63;
    const int g    = lane >> 4;
    const int l16  = lane & 15;
    const int slot = blockIdx.x * 4 + wave;
    if (slot >= M) return;
    const int n = nodemap[slot];

    float sc[8], sh[8];
    if (AFF){
        #pragma unroll
        for (int j = 0; j < 8; ++j){
            sc[j] = cs[256 + l16 * 8 + j];
            sh[j] = cs[384 + l16 * 8 + j];
        }
    }

    const int beg = indptr[n], end = indptr[n + 1];
    float s[8];
    #pragma unroll
    for (int i = 0; i < 8; ++i) s[i] = 0.f;

    for (int e0 = beg; e0 < end; e0 += 16){
        uint4 v[4];
        #pragma unroll
        for (int u = 0; u < 4; ++u){
            int e = e0 + u * 4 + g;
            if (e < end){
                int idx = esrc[e];
                v[u] = *(const uint4*)(h + (size_t)idx * 128 + l16 * 8);
            }
        }
        #pragma unroll
        for (int u = 0; u < 4; ++u){
            int e = e0 + u * 4 + g;
            if (e < end){
                float f;
                f = bits2f(v[u].x << 16);         if (AFF) f = fmaxf(fmaf(f, sc[0], sh[0]), 0.f); s[0] += f;
                f = bits2f(v[u].x & 0xffff0000u); if (AFF) f = fmaxf(fmaf(f, sc[1], sh[1]), 0.f); s[1] += f;
                f = bits2f(v[u].y << 16);         if (AFF) f = fmaxf(fmaf(f, sc[2], sh[2]), 0.f); s[2] += f;
                f = bits2f(v[u].y & 0xffff0000u); if (AFF) f = fmaxf(fmaf(f, sc[3], sh[3]), 0.f); s[3] += f;
                f = bits2f(v[u].z << 16);         if (AFF) f = fmaxf(fmaf(f, sc[4], sh[4]), 0.f); s[4] += f;
                f = bits2f(v[u].z & 0xffff0000u); if (AFF) f = fmaxf(fmaf(f, sc[5], sh[5]), 0.f); s[5] += f;
                f = bits2f(v[u].w << 16);         if (AFF) f = fmaxf(fmaf(f, sc[6], sh[6]), 0.f); s[6] += f;
                f = bits2f(v[u].w & 0xffff0000u); if (AFF) f = fmaxf(fmaf(f, sc[7], sh[7]), 0.f); s[7] += f;
            }
        }
    }

    #pragma unroll
    for (int i = 0; i < 8; ++i){
        s[i] += __shfl_xor(s[i], 16);
        s[i] += __shfl_xor(s[i], 32);
    }

    if (g == 0){
        float fs = invdeg[n];
        uint4 o;
        o.x = (u32)f2bf(s[0] * fs) | ((u32)f2bf(s[1] * fs) << 16);
        o.y = (u32)f2bf(s[2] * fs) | ((u32)f2bf(s[3] * fs) << 16);
        o.z = (u32)f2bf(s[4] * fs) | ((u32)f2bf(s[5] * fs) << 16);
        o.w = (u32)f2bf(s[6] * fs) | ((u32)f2bf(s[7] * fs) << 16);
        *(uint4*)(agg + (size_t)n * 128 + l16 * 8) = o;
    }
}

// ------- GEMM: B pinned in registers, A streamed (ping-pong), fused bias + BN stats -------
// STATS: bf16 pre staged through per-wave LDS and stored as full-line dwordx4.
// AFFA: A-self rows get relu(fma) from LDS scale/shift before MFMA.

template<int NTW, bool STATS, bool AFFA>
__global__ __launch_bounds__(256, 2) void gemm2_kernel(const u16* __restrict__ hA,
                                                       const u16* __restrict__ aggA,
                                                       const u16* __restrict__ Bp,
                                                       const float* __restrict__ bias,
                                                       const float* __restrict__ cs,
                                                       void* __restrict__ outPre,
                                                       float* __restrict__ partials,
                                                       int M, int T, int nstream){
    constexpr int N = NTW * 32;
    __shared__ float sbuf[4][N], s2buf[4][N];
    __shared__ float s_sc[128], s_sh[128];
    __shared__ u16 stg[4][16][64];   // per-wave store staging (16 rows x 64 cols bf16)
    const int wave = threadIdx.x >> 6;
    const int lane = threadIdx.x & 63;
    const int m15 = lane & 15;
    const int quad = lane >> 4;
    const int colbase = (wave & 1) * (NTW * 16);

    if (STATS){
        for (int i = threadIdx.x; i < 4 * N; i += 256){
            ((float*)sbuf)[i] = 0.f;
            ((float*)s2buf)[i] = 0.f;
        }
    }
    if (AFFA && threadIdx.x < 128){
        s_sc[threadIdx.x] = cs[256 + threadIdx.x];
        s_sh[threadIdx.x] = cs[384 + threadIdx.x];
    }
    if (STATS || AFFA) __syncthreads();

    short8 breg[NTW][8];
    float bv[NTW];
    #pragma unroll
    for (int nt = 0; nt < NTW; ++nt){
        bv[nt] = bias[colbase + nt * 16 + m15];
        #pragma unroll
        for (int k0 = 0; k0 < 8; ++k0)
            breg[nt][k0] = *(const short8*)(Bp + (size_t)(colbase + nt * 16 + m15) * 256 + k0 * 32 + quad * 8);
    }

    float sS[NTW], sQ[NTW];
    #pragma unroll
    for (int nt = 0; nt < NTW; ++nt){ sS[nt] = 0.f; sQ[nt] = 0.f; }

    auto loadA = [&](short8* buf, int tile){
        int arow = tile * 16 + m15;
        if (arow >= M) arow = M - 1;
        const u16* p0 = hA   + (size_t)arow * 128 + quad * 8;
        const u16* p1 = aggA + (size_t)arow * 128 + quad * 8;
        #pragma unroll
        for (int k0 = 0; k0 < 4; ++k0) buf[k0]     = *(const short8*)(p0 + k0 * 32);
        #pragma unroll
        for (int k0 = 0; k0 < 4; ++k0) buf[4 + k0] = *(const short8*)(p1 + k0 * 32);
    };

    auto compute = [&](short8* buf, int tile){
        if (AFFA){
            #pragma unroll
            for (int k0 = 0; k0 < 4; ++k0){
                const int cb = k0 * 32 + quad * 8;
                short8 raw = buf[k0];
                #pragma unroll
                for (int j = 0; j < 8; ++j){
                    float f = bits2f(((u32)(u16)raw[j]) << 16);
                    f = fmaxf(fmaf(f, s_sc[cb + j], s_sh[cb + j]), 0.f);
                    raw[j] = (short)f2bf(f);
                }
                buf[k0] = raw;
            }
        }
        floatx4 acc[NTW];
        #pragma unroll
        for (int nt = 0; nt < NTW; ++nt) acc[nt] = 0.0f;
        #pragma unroll
        for (int k0 = 0; k0 < 8; ++k0)
            #pragma unroll
            for (int nt = 0; nt < NTW; ++nt)
                acc[nt] = __builtin_amdgcn_mfma_f32_16x16x32_bf16(buf[k0], breg[nt][k0], acc[nt], 0, 0, 0);
        const int row0 = tile * 16 + quad * 4;
        #pragma unroll
        for (int nt = 0; nt < NTW; ++nt){
            const int col = colbase + nt * 16 + m15;
            #pragma unroll
            for (int r = 0; r < 4; ++r){
                int row = row0 + r;
                float v = acc[nt][r] + bv[nt];
                if (STATS){
                    stg[wave][quad * 4 + r][nt * 16 + m15] = f2bf(v);
                    if (row < M){
                        sS[nt] += v;
                        sQ[nt] = fmaf(v, v, sQ[nt]);
                    }
                } else {
                    if (row < M)
                        ((float*)outPre)[(size_t)row * N + col] = v;
                }
            }
        }
        if (STATS){
            // full-line write-out: 2 passes x (64 lanes x 16 B contiguous per 8 rows)
            const int r8    = lane >> 3;        // 0..7
            const int chunk = lane & 7;         // 16-B chunk within 128-B row segment
            #pragma unroll
            for (int half = 0; half < 2; ++half){
                int r = half * 8 + r8;
                int grow = tile * 16 + r;
                uint4 val = *(const uint4*)&stg[wave][r][chunk * 8];
                if (grow < M)
                    *(uint4*)((u16*)outPre + (size_t)grow * N + colbase + chunk * 8) = val;
            }
        }
    };

    short8 A0[8], A1[8];
    int t = blockIdx.x * 2 + (wave >> 1);
    const int stride = nstream;
    if (t < T){
        loadA(A0, t);
        while (true){
            int tn = t + stride;
            if (tn < T) loadA(A1, tn);
            compute(A0, t);
            t = tn;
            if (t >= T) break;
            tn = t + stride;
            if (tn < T) loadA(A0, tn);
            compute(A1, t);
            t = tn;
            if (t >= T) break;
        }
    }

    if (STATS){
        #pragma unroll
        for (int nt = 0; nt < NTW; ++nt){
            float s = sS[nt], q = sQ[nt];
            s += __shfl_xor(s, 16);  s += __shfl_xor(s, 32);
            q += __shfl_xor(q, 16);  q += __shfl_xor(q, 32);
            if (lane < 16){
                sbuf[wave][colbase + nt * 16 + m15] = s;
                s2buf[wave][colbase + nt * 16 + m15] = q;
            }
        }
        __syncthreads();
        const int c = threadIdx.x;
        if (c < N){
            float S  = sbuf[0][c] + sbuf[1][c] + sbuf[2][c] + sbuf[3][c];
            float S2 = s2buf[0][c] + s2buf[1][c] + s2buf[2][c] + s2buf[3][c];
            partials[(size_t)blockIdx.x * (2 * N) + c]     = S;
            partials[(size_t)blockIdx.x * (2 * N) + N + c] = S2;
        }
    }
}

// ---------------- BN: reduce block partials; finalize scale/shift ----------------

__global__ __launch_bounds__(256) void bnred_kernel(const float* __restrict__ partials,
                                                    float* __restrict__ cs, int nblk){
    const int t = threadIdx.x;
    float s = 0.f;
    for (int b = blockIdx.x; b < nblk; b += (int)gridDim.x)
        s += partials[(size_t)b * 256 + t];
    atomicAdd(&cs[t], s);
}

__global__ void bnfin_kernel(float* __restrict__ cs, const float* __restrict__ gamma,
                             const float* __restrict__ beta, float invM){
    int c = threadIdx.x;  // 128
    float mu  = cs[c] * invM;
    float var = fmaxf(cs[128 + c] * invM - mu * mu, 0.0f);
    float sc  = gamma[c] * rsqrtf(var + 1e-5f);
    cs[256 + c] = sc;
    cs[384 + c] = beta[c] - mu * sc;
}

// ---------------- log_softmax (one wave per 64-wide row) ----------------

__global__ __launch_bounds__(256) void lsm_kernel(const float* __restrict__ pre,
                                                  float* __restrict__ out, int M){
    const int wave = threadIdx.x >> 6;
    const int lane = threadIdx.x & 63;
    const int row = blockIdx.x * 4 + wave;
    if (row >= M) return;
    float v = pre[(size_t)row * 64 + lane];
    float m = v;
    #pragma unroll
    for (int o = 32; o; o >>= 1) m = fmaxf(m, __shfl_xor(m, o));
    float e = __expf(v - m);
    float s = e;
    #pragma unroll
    for (int o = 32; o; o >>= 1) s += __shfl_xor(s, o);
    out[(size_t)row * 64 + lane] = v - m - __logf(s);
}

// ---------------- host ----------------

extern "C" void kernel_launch(void* const* d_in, const int* in_sizes, int n_in,
                              void* d_out, int out_size, void* d_ws, size_t ws_size,
                              hipStream_t stream) {
    const float* x   = (const float*)d_in[0];
    const int*   src = (const int*)d_in[1];
    const int*   dst = (const int*)d_in[2];
    const float* wself[3]  = {(const float*)d_in[3], (const float*)d_in[6], (const float*)d_in[9]};
    const float* wneigh[3] = {(const float*)d_in[4], (const float*)d_in[7], (const float*)d_in[10]};
    const float* bias[3]   = {(const float*)d_in[5], (const float*)d_in[8], (const float*)d_in[11]};
    const float* gamma[2]  = {(const float*)d_in[12], (const float*)d_in[14]};
    const float* beta[2]   = {(const float*)d_in[13], (const float*)d_in[15]};

    const int M = in_sizes[0] / 128;   // 100000
    const int E = in_sizes[1];         // 1600000
    const int NBUK = (M + 511) / 512;  // 196
    const int T = (M + 15) / 16;
    const int GB = 512;

    char* ws = (char*)d_ws;
    size_t off = 0;
    auto alloc = [&](size_t bytes) -> void* {
        void* p = ws + off;
        off = (off + bytes + 511) & ~(size_t)511;
        return p;
    };
    int*   gbcnt  = (int*)alloc(256 * 4);
    int*   bbase  = (int*)alloc(256 * 4);
    int*   bcur   = (int*)alloc(256 * 4);
    int*   dh     = (int*)alloc(64 * 4);
    int*   dcur   = (int*)alloc(64 * 4);
    int*   indptr = (int*)alloc((size_t)(M + 1) * 4);
    int*   nodemap= (int*)alloc((size_t)M * 4);
    u32*   pairs  = (u32*)alloc((size_t)E * 4);
    int*   esrc   = (int*)alloc((size_t)E * 4);
    float* invdeg = (float*)alloc((size_t)M * 4);
    u16* bpack0 = (u16*)alloc(128 * 256 * 2);
    u16* bpack1 = (u16*)alloc(128 * 256 * 2);
    u16* bpack2 = (u16*)alloc(64 * 256 * 2);
    float* colstat0 = (float*)alloc(512 * 4);
    float* colstat1 = (float*)alloc(512 * 4);
    float* partials = (float*)alloc((size_t)GB * 256 * 4);
    u16*   hbuf   = (u16*)alloc((size_t)M * 128 * 2);   // bf16(x)
    u16*   aggbuf = (u16*)alloc((size_t)M * 128 * 2);
    u16*   preA   = (u16*)alloc((size_t)M * 128 * 2);   // layer0 pre-BN (bf16)
    u16*   preB   = (u16*)alloc((size_t)M * 128 * 2);   // layer1 pre-BN (bf16)
    float* preF   = (float*)alloc((size_t)M * 64 * 4);  // final logits (f32)

    // --- CSR build ---
    hipMemsetAsync(gbcnt, 0, 256 * 4, stream);
    bhist_kernel<<<(E + 8191) / 8192, 256, 0, stream>>>(dst, gbcnt, E);
    bscan_kernel<<<1, 256, 0, stream>>>(gbcnt, bbase, bcur, NBUK);
    bin_kernel<<<(E + BIN_TILE - 1) / BIN_TILE, 256, 0, stream>>>(src, dst, bcur, pairs, E, NBUK);
    sort2_kernel<<<NBUK, 256, 0, stream>>>(pairs, bbase, indptr, invdeg, esrc, M, E, NBUK);

    // --- degree-balanced node ordering ---
    hipMemsetAsync(dh, 0, 64 * 4, stream);
    deghist_kernel<<<(M + 8191) / 8192, 256, 0, stream>>>(indptr, dh, M);
    degscan_kernel<<<1, 64, 0, stream>>>(dh, dcur);
    degplace_kernel<<<(M + 4095) / 4096, 256, 0, stream>>>(indptr, dcur, nodemap, M);

    // --- bf16 convert + weight pack ---
    cvt_kernel<<<((M * 32) + 255) / 256, 256, 0, stream>>>(x, hbuf, M * 32);
    pack_kernel<<<(128 * 256 + 255) / 256, 256, 0, stream>>>(wself[0], wneigh[0], bpack0, 128);
    pack_kernel<<<(128 * 256 + 255) / 256, 256, 0, stream>>>(wself[1], wneigh[1], bpack1, 128);
    pack_kernel<<<(64 * 256 + 255) / 256, 256, 0, stream>>>(wself[2], wneigh[2], bpack2, 64);

    // --- layer 0 ---
    agg_kernel<false><<<(M + 3) / 4, 256, 0, stream>>>(hbuf, indptr, esrc, invdeg, nullptr, nodemap, aggbuf, M);
    gemm2_kernel<4, true, false><<<GB, 256, 0, stream>>>(hbuf, aggbuf, bpack0, bias[0], nullptr,
                                                         preA, partials, M, T, GB * 2);
    hipMemsetAsync(colstat0, 0, 256 * 4, stream);
    bnred_kernel<<<32, 256, 0, stream>>>(partials, colstat0, GB);
    bnfin_kernel<<<1, 128, 0, stream>>>(colstat0, gamma[0], beta[0], 1.0f / (float)M);

    // --- layer 1 ---
    agg_kernel<true><<<(M + 3) / 4, 256, 0, stream>>>(preA, indptr, esrc, invdeg, colstat0, nodemap, aggbuf, M);
    gemm2_kernel<4, true, true><<<GB, 256, 0, stream>>>(preA, aggbuf, bpack1, bias[1], colstat0,
                                                        preB, partials, M, T, GB * 2);
    hipMemsetAsync(colstat1, 0, 256 * 4, stream);
    bnred_kernel<<<32, 256, 0, stream>>>(partials, colstat1, GB);
    bnfin_kernel<<<1, 128, 0, stream>>>(colstat1, gamma[1], beta[1], 1.0f / (float)M);

    // --- layer 2 ---
    agg_kernel<true><<<(M + 3) / 4, 256, 0, stream>>>(preB, indptr, esrc, invdeg, colstat1, nodemap, aggbuf, M);
    gemm2_kernel<2, false, true><<<GB, 256, 0, stream>>>(preB, aggbuf, bpack2, bias[2], colstat1,
                                                         preF, partials, M, T, GB * 2);
    lsm_kernel<<<(M + 3) / 4, 256, 0, stream>>>(preF, (float*)d_out, M);
}

// Round 10
// 536.453 us; speedup vs baseline: 1.0790x; 1.0790x over previous
//
#include <hip/hip_runtime.h>
#include <hip/hip_bf16.h>

typedef unsigned short u16;
typedef unsigned int   u32;
typedef __attribute__((ext_vector_type(8))) short short8;
typedef __attribute__((ext_vector_type(4))) float floatx4;
typedef __attribute__((ext_vector_type(2))) float floatx2;

__device__ __forceinline__ float bits2f(u32 v){ float f; __builtin_memcpy(&f, &v, 4); return f; }
__device__ __forceinline__ u16 f2bf(float f){
    __hip_bfloat16 h = __float2bfloat16(f);
    u16 u; __builtin_memcpy(&u, &h, 2); return u;
}

// ---------------- f32 -> bf16 conversion (x into hbuf) ----------------

__global__ __launch_bounds__(256) void cvt_kernel(const float* __restrict__ in,
                                                  u16* __restrict__ out, int total4){
    int i = blockIdx.x * 256 + threadIdx.x;
    if (i >= total4) return;
    float4 v = ((const float4*)in)[i];
    uint2 o;
    o.x = (u32)f2bf(v.x) | ((u32)f2bf(v.y) << 16);
    o.y = (u32)f2bf(v.z) | ((u32)f2bf(v.w) << 16);
    ((uint2*)out)[i] = o;
}

// ---------------- CSR build: bucket hist -> bucket scan -> multisplit bin -> bucket sort ----------------

__global__ __launch_bounds__(256) void bhist_kernel(const int* __restrict__ dst,
                                                    int* __restrict__ gbcnt, int E){
    __shared__ int bc[256];
    const int t = threadIdx.x;
    bc[t] = 0;
    __syncthreads();
    const int tile0 = blockIdx.x * 8192;
    const int cnt = min(8192, E - tile0);
    for (int j = t; j < cnt; j += 256) atomicAdd(&bc[dst[tile0 + j] >> 9], 1);
    __syncthreads();
    if (bc[t] > 0) atomicAdd(&gbcnt[t], bc[t]);
}

__global__ __launch_bounds__(256) void bscan_kernel(const int* __restrict__ gbcnt,
                                                    int* __restrict__ bbase,
                                                    int* __restrict__ bcur, int nbuk){
    __shared__ int ws[4];
    const int t = threadIdx.x, lane = t & 63, wv = t >> 6;
    int v = (t < nbuk) ? gbcnt[t] : 0;
    int s = v;
    for (int off = 1; off < 64; off <<= 1){
        int n = __shfl_up(s, off);
        if (lane >= off) s += n;
    }
    if (lane == 63) ws[wv] = s;
    __syncthreads();
    int woff = 0;
    for (int w = 0; w < wv; ++w) woff += ws[w];
    int excl = s + woff - v;
    if (t < nbuk){ bbase[t] = excl; bcur[t] = excl; }
}

#define BIN_TILE 8192
__global__ __launch_bounds__(256) void bin_kernel(const int* __restrict__ src,
                                                  const int* __restrict__ dst,
                                                  int* __restrict__ bcur,
                                                  u32* __restrict__ pairs, int E, int nbuk){
    __shared__ u32 hcnt[256], hexcl[256], hoff[256];
    __shared__ int gbase[256];
    __shared__ u32 stage[BIN_TILE];
    __shared__ unsigned char bkt[BIN_TILE];
    const int t = threadIdx.x;
    const int tile0 = blockIdx.x * BIN_TILE;
    const int cntE = min(BIN_TILE, E - tile0);

    hcnt[t] = 0;
    __syncthreads();
    for (int j = t; j < cntE; j += 256){
        int d = dst[tile0 + j];
        atomicAdd(&hcnt[d >> 9], 1u);
    }
    __syncthreads();
    if (t < 64){
        u32 a0 = hcnt[4*t], a1 = hcnt[4*t+1], a2 = hcnt[4*t+2], a3 = hcnt[4*t+3];
        u32 lsum = a0 + a1 + a2 + a3;
        u32 s = lsum;
        for (int off = 1; off < 64; off <<= 1){
            u32 n = __shfl_up(s, off);
            if (t >= off) s += n;
        }
        u32 base = s - lsum;
        hexcl[4*t]   = base;
        hexcl[4*t+1] = base + a0;
        hexcl[4*t+2] = base + a0 + a1;
        hexcl[4*t+3] = base + a0 + a1 + a2;
        hoff[4*t]   = base;
        hoff[4*t+1] = base + a0;
        hoff[4*t+2] = base + a0 + a1;
        hoff[4*t+3] = base + a0 + a1 + a2;
    }
    __syncthreads();
    if (t < nbuk && hcnt[t] > 0) gbase[t] = atomicAdd(&bcur[t], (int)hcnt[t]);
    for (int j = t; j < cntE; j += 256){
        int d = dst[tile0 + j];
        int s = src[tile0 + j];
        int b = d >> 9;
        u32 p = atomicAdd(&hoff[b], 1u);
        stage[p] = ((u32)s << 9) | (u32)(d & 511);
        bkt[p] = (unsigned char)b;
    }
    __syncthreads();
    for (int j = t; j < cntE; j += 256){
        int b = bkt[j];
        pairs[gbase[b] + (int)((u32)j - hexcl[b])] = stage[j];
    }
}

__global__ __launch_bounds__(256) void sort2_kernel(const u32* __restrict__ pairs,
                                                    const int* __restrict__ bbase,
                                                    int* __restrict__ indptr,
                                                    float* __restrict__ invdeg,
                                                    int* __restrict__ esrc,
                                                    int M, int E, int nbuk){
    __shared__ int ndeg[512];
    __shared__ int cur[512];
    __shared__ int wsI[4];
    const int b = blockIdx.x;
    const int node0 = b * 512;
    const int lo = bbase[b];
    const int hi = (b + 1 < nbuk) ? bbase[b + 1] : E;
    const int t = threadIdx.x, lane = t & 63, wv = t >> 6;

    ndeg[t] = 0; ndeg[t + 256] = 0;
    __syncthreads();
    for (int i = lo + t; i < hi; i += 256) atomicAdd(&ndeg[pairs[i] & 511], 1);
    __syncthreads();

    const int d0 = ndeg[2*t], d1 = ndeg[2*t + 1];
    const int p = d0 + d1;
    int s = p;
    for (int off = 1; off < 64; off <<= 1){
        int n = __shfl_up(s, off);
        if (lane >= off) s += n;
    }
    if (lane == 63) wsI[wv] = s;
    __syncthreads();
    int woff = 0;
    for (int w = 0; w < wv; ++w) woff += wsI[w];
    const int incl = s + woff;
    const int excl0 = incl - p;
    const int excl1 = excl0 + d0;

    const int n0 = node0 + 2*t, n1 = node0 + 2*t + 1;
    if (n0 < M){
        indptr[n0 + 1] = lo + excl0 + d0;
        invdeg[n0] = 1.0f / (float)max(d0, 1);
        cur[2*t] = lo + excl0;
    }
    if (n1 < M){
        indptr[n1 + 1] = lo + excl1 + d1;
        invdeg[n1] = 1.0f / (float)max(d1, 1);
        cur[2*t + 1] = lo + excl1;
    }
    if (b == 0 && t == 0) indptr[0] = 0;
    __syncthreads();
    for (int i = lo + t; i < hi; i += 256){
        u32 v = pairs[i];
        int pos = atomicAdd(&cur[v & 511], 1);
        esrc[pos] = (int)(v >> 9);
    }
}

// ------- weight packing -------

__global__ void pack_kernel(const float* __restrict__ wself, const float* __restrict__ wneigh,
                            u16* __restrict__ bp, int N){
    int i = blockIdx.x * 256 + threadIdx.x;
    if (i >= N * 256) return;
    int n = i >> 8, k = i & 255;
    float v = (k < 128) ? wself[k * N + n] : wneigh[(k - 128) * N + n];
    bp[i] = f2bf(v);
}

// ---------------- aggregation (packed-f32 accumulate, optional fused affine+ReLU) -------

template<bool AFF>
__global__ __launch_bounds__(256) void agg_kernel(const u16* __restrict__ h,
                                                  const int* __restrict__ indptr,
                                                  const int* __restrict__ esrc,
                                                  const float* __restrict__ invdeg,
                                                  const float* __restrict__ cs,
                                                  u16* __restrict__ agg, int M){
    const int wave = threadIdx.x >> 6;
    const int lane = threadIdx.x & 63;
    const int g    = lane >> 4;
    const int l16  = lane & 15;
    const int n = blockIdx.x * 4 + wave;
    if (n >= M) return;

    floatx2 scv[4], shv[4];
    if (AFF){
        #pragma unroll
        for (int j = 0; j < 4; ++j){
            scv[j].x = cs[256 + l16 * 8 + 2*j];
            scv[j].y = cs[256 + l16 * 8 + 2*j + 1];
            shv[j].x = cs[384 + l16 * 8 + 2*j];
            shv[j].y = cs[384 + l16 * 8 + 2*j + 1];
        }
    }

    const int beg = indptr[n], end = indptr[n + 1];
    floatx2 acc[4];
    #pragma unroll
    for (int i = 0; i < 4; ++i){ acc[i].x = 0.f; acc[i].y = 0.f; }

    #pragma unroll 2
    for (int e0 = beg; e0 < end; e0 += 16){
        uint4 v[4];
        #pragma unroll
        for (int u = 0; u < 4; ++u){
            int e = e0 + u * 4 + g;
            if (e < end){
                int idx = esrc[e];
                v[u] = *(const uint4*)(h + (size_t)idx * 128 + l16 * 8);
            }
        }
        #pragma unroll
        for (int u = 0; u < 4; ++u){
            int e = e0 + u * 4 + g;
            if (e < end){
                u32 w[4] = {v[u].x, v[u].y, v[u].z, v[u].w};
                #pragma unroll
                for (int j = 0; j < 4; ++j){
                    floatx2 t;
                    t.x = bits2f(w[j] << 16);
                    t.y = bits2f(w[j] & 0xffff0000u);
                    if (AFF){
                        t = t * scv[j] + shv[j];     // v_pk_fma_f32
                        t.x = fmaxf(t.x, 0.f);
                        t.y = fmaxf(t.y, 0.f);
                    }
                    acc[j] += t;                     // v_pk_add_f32
                }
            }
        }
    }

    float s[8];
    #pragma unroll
    for (int j = 0; j < 4; ++j){ s[2*j] = acc[j].x; s[2*j+1] = acc[j].y; }
    #pragma unroll
    for (int i = 0; i < 8; ++i){
        s[i] += __shfl_xor(s[i], 16);
        s[i] += __shfl_xor(s[i], 32);
    }

    if (g == 0){
        float fs = invdeg[n];
        uint4 o;
        o.x = (u32)f2bf(s[0] * fs) | ((u32)f2bf(s[1] * fs) << 16);
        o.y = (u32)f2bf(s[2] * fs) | ((u32)f2bf(s[3] * fs) << 16);
        o.z = (u32)f2bf(s[4] * fs) | ((u32)f2bf(s[5] * fs) << 16);
        o.w = (u32)f2bf(s[6] * fs) | ((u32)f2bf(s[7] * fs) << 16);
        *(uint4*)(agg + (size_t)n * 128 + l16 * 8) = o;
    }
}

// ------- GEMM: B pinned in registers, A streamed (ping-pong), fused bias + BN stats -------
// (direct stores — R9's LDS staging regressed: 8-way bank conflicts)

template<int NTW, bool STATS, bool AFFA>
__global__ __launch_bounds__(256, 2) void gemm2_kernel(const u16* __restrict__ hA,
                                                       const u16* __restrict__ aggA,
                                                       const u16* __restrict__ Bp,
                                                       const float* __restrict__ bias,
                                                       const float* __restrict__ cs,
                                                       void* __restrict__ outPre,
                                                       float* __restrict__ partials,
                                                       int M, int T, int nstream){
    constexpr int N = NTW * 32;
    __shared__ float sbuf[4][N], s2buf[4][N];
    __shared__ float s_sc[128], s_sh[128];
    const int wave = threadIdx.x >> 6;
    const int lane = threadIdx.x & 63;
    const int m15 = lane & 15;
    const int quad = lane >> 4;
    const int colbase = (wave & 1) * (NTW * 16);

    if (STATS){
        for (int i = threadIdx.x; i < 4 * N; i += 256){
            ((float*)sbuf)[i] = 0.f;
            ((float*)s2buf)[i] = 0.f;
        }
    }
    if (AFFA && threadIdx.x < 128){
        s_sc[threadIdx.x] = cs[256 + threadIdx.x];
        s_sh[threadIdx.x] = cs[384 + threadIdx.x];
    }
    if (STATS || AFFA) __syncthreads();

    short8 breg[NTW][8];
    float bv[NTW];
    #pragma unroll
    for (int nt = 0; nt < NTW; ++nt){
        bv[nt] = bias[colbase + nt * 16 + m15];
        #pragma unroll
        for (int k0 = 0; k0 < 8; ++k0)
            breg[nt][k0] = *(const short8*)(Bp + (size_t)(colbase + nt * 16 + m15) * 256 + k0 * 32 + quad * 8);
    }

    float sS[NTW], sQ[NTW];
    #pragma unroll
    for (int nt = 0; nt < NTW; ++nt){ sS[nt] = 0.f; sQ[nt] = 0.f; }

    auto loadA = [&](short8* buf, int tile){
        int arow = tile * 16 + m15;
        if (arow >= M) arow = M - 1;
        const u16* p0 = hA   + (size_t)arow * 128 + quad * 8;
        const u16* p1 = aggA + (size_t)arow * 128 + quad * 8;
        #pragma unroll
        for (int k0 = 0; k0 < 4; ++k0) buf[k0]     = *(const short8*)(p0 + k0 * 32);
        #pragma unroll
        for (int k0 = 0; k0 < 4; ++k0) buf[4 + k0] = *(const short8*)(p1 + k0 * 32);
    };

    auto compute = [&](short8* buf, int tile){
        if (AFFA){
            #pragma unroll
            for (int k0 = 0; k0 < 4; ++k0){
                const int cb = k0 * 32 + quad * 8;
                short8 raw = buf[k0];
                #pragma unroll
                for (int j = 0; j < 8; ++j){
                    float f = bits2f(((u32)(u16)raw[j]) << 16);
                    f = fmaxf(fmaf(f, s_sc[cb + j], s_sh[cb + j]), 0.f);
                    raw[j] = (short)f2bf(f);
                }
                buf[k0] = raw;
            }
        }
        floatx4 acc[NTW];
        #pragma unroll
        for (int nt = 0; nt < NTW; ++nt) acc[nt] = 0.0f;
        #pragma unroll
        for (int k0 = 0; k0 < 8; ++k0)
            #pragma unroll
            for (int nt = 0; nt < NTW; ++nt)
                acc[nt] = __builtin_amdgcn_mfma_f32_16x16x32_bf16(buf[k0], breg[nt][k0], acc[nt], 0, 0, 0);
        const int row0 = tile * 16 + quad * 4;
        #pragma unroll
        for (int nt = 0; nt < NTW; ++nt){
            const int col = colbase + nt * 16 + m15;
            #pragma unroll
            for (int r = 0; r < 4; ++r){
                int row = row0 + r;
                if (row < M){
                    float v = acc[nt][r] + bv[nt];
                    if (STATS){
                        ((u16*)outPre)[(size_t)row * N + col] = f2bf(v);
                        sS[nt] += v;
                        sQ[nt] = fmaf(v, v, sQ[nt]);
                    } else {
                        ((float*)outPre)[(size_t)row * N + col] = v;
                    }
                }
            }
        }
    };

    short8 A0[8], A1[8];
    int t = blockIdx.x * 2 + (wave >> 1);
    const int stride = nstream;
    if (t < T){
        loadA(A0, t);
        while (true){
            int tn = t + stride;
            if (tn < T) loadA(A1, tn);
            compute(A0, t);
            t = tn;
            if (t >= T) break;
            tn = t + stride;
            if (tn < T) loadA(A0, tn);
            compute(A1, t);
            t = tn;
            if (t >= T) break;
        }
    }

    if (STATS){
        #pragma unroll
        for (int nt = 0; nt < NTW; ++nt){
            float s = sS[nt], q = sQ[nt];
            s += __shfl_xor(s, 16);  s += __shfl_xor(s, 32);
            q += __shfl_xor(q, 16);  q += __shfl_xor(q, 32);
            if (lane < 16){
                sbuf[wave][colbase + nt * 16 + m15] = s;
                s2buf[wave][colbase + nt * 16 + m15] = q;
            }
        }
        __syncthreads();
        const int c = threadIdx.x;
        if (c < N){
            float S  = sbuf[0][c] + sbuf[1][c] + sbuf[2][c] + sbuf[3][c];
            float S2 = s2buf[0][c] + s2buf[1][c] + s2buf[2][c] + s2buf[3][c];
            partials[(size_t)blockIdx.x * (2 * N) + c]     = S;
            partials[(size_t)blockIdx.x * (2 * N) + N + c] = S2;
        }
    }
}

// ---------------- BN: reduce block partials; finalize scale/shift ----------------

__global__ __launch_bounds__(256) void bnred_kernel(const float* __restrict__ partials,
                                                    float* __restrict__ cs, int nblk){
    const int t = threadIdx.x;
    float s = 0.f;
    for (int b = blockIdx.x; b < nblk; b += (int)gridDim.x)
        s += partials[(size_t)b * 256 + t];
    atomicAdd(&cs[t], s);
}

__global__ void bnfin_kernel(float* __restrict__ cs, const float* __restrict__ gamma,
                             const float* __restrict__ beta, float invM){
    int c = threadIdx.x;  // 128
    float mu  = cs[c] * invM;
    float var = fmaxf(cs[128 + c] * invM - mu * mu, 0.0f);
    float sc  = gamma[c] * rsqrtf(var + 1e-5f);
    cs[256 + c] = sc;
    cs[384 + c] = beta[c] - mu * sc;
}

// ---------------- log_softmax (one wave per 64-wide row) ----------------

__global__ __launch_bounds__(256) void lsm_kernel(const float* __restrict__ pre,
                                                  float* __restrict__ out, int M){
    const int wave = threadIdx.x >> 6;
    const int lane = threadIdx.x & 63;
    const int row = blockIdx.x * 4 + wave;
    if (row >= M) return;
    float v = pre[(size_t)row * 64 + lane];
    float m = v;
    #pragma unroll
    for (int o = 32; o; o >>= 1) m = fmaxf(m, __shfl_xor(m, o));
    float e = __expf(v - m);
    float s = e;
    #pragma unroll
    for (int o = 32; o; o >>= 1) s += __shfl_xor(s, o);
    out[(size_t)row * 64 + lane] = v - m - __logf(s);
}

// ---------------- host ----------------

extern "C" void kernel_launch(void* const* d_in, const int* in_sizes, int n_in,
                              void* d_out, int out_size, void* d_ws, size_t ws_size,
                              hipStream_t stream) {
    const float* x   = (const float*)d_in[0];
    const int*   src = (const int*)d_in[1];
    const int*   dst = (const int*)d_in[2];
    const float* wself[3]  = {(const float*)d_in[3], (const float*)d_in[6], (const float*)d_in[9]};
    const float* wneigh[3] = {(const float*)d_in[4], (const float*)d_in[7], (const float*)d_in[10]};
    const float* bias[3]   = {(const float*)d_in[5], (const float*)d_in[8], (const float*)d_in[11]};
    const float* gamma[2]  = {(const float*)d_in[12], (const float*)d_in[14]};
    const float* beta[2]   = {(const float*)d_in[13], (const float*)d_in[15]};

    const int M = in_sizes[0] / 128;   // 100000
    const int E = in_sizes[1];         // 1600000
    const int NBUK = (M + 511) / 512;  // 196
    const int T = (M + 15) / 16;
    const int GB = 512;

    char* ws = (char*)d_ws;
    size_t off = 0;
    auto alloc = [&](size_t bytes) -> void* {
        void* p = ws + off;
        off = (off + bytes + 511) & ~(size_t)511;
        return p;
    };
    int*   gbcnt  = (int*)alloc(256 * 4);
    int*   bbase  = (int*)alloc(256 * 4);
    int*   bcur   = (int*)alloc(256 * 4);
    int*   indptr = (int*)alloc((size_t)(M + 1) * 4);
    u32*   pairs  = (u32*)alloc((size_t)E * 4);
    int*   esrc   = (int*)alloc((size_t)E * 4);
    float* invdeg = (float*)alloc((size_t)M * 4);
    u16* bpack0 = (u16*)alloc(128 * 256 * 2);
    u16* bpack1 = (u16*)alloc(128 * 256 * 2);
    u16* bpack2 = (u16*)alloc(64 * 256 * 2);
    float* colstat0 = (float*)alloc(512 * 4);
    float* colstat1 = (float*)alloc(512 * 4);
    float* partials = (float*)alloc((size_t)GB * 256 * 4);
    u16*   hbuf   = (u16*)alloc((size_t)M * 128 * 2);   // bf16(x)
    u16*   aggbuf = (u16*)alloc((size_t)M * 128 * 2);
    u16*   preA   = (u16*)alloc((size_t)M * 128 * 2);   // layer0 pre-BN (bf16)
    u16*   preB   = (u16*)alloc((size_t)M * 128 * 2);   // layer1 pre-BN (bf16)
    float* preF   = (float*)alloc((size_t)M * 64 * 4);  // final logits (f32)

    // --- CSR build ---
    hipMemsetAsync(gbcnt, 0, 256 * 4, stream);
    bhist_kernel<<<(E + 8191) / 8192, 256, 0, stream>>>(dst, gbcnt, E);
    bscan_kernel<<<1, 256, 0, stream>>>(gbcnt, bbase, bcur, NBUK);
    bin_kernel<<<(E + BIN_TILE - 1) / BIN_TILE, 256, 0, stream>>>(src, dst, bcur, pairs, E, NBUK);
    sort2_kernel<<<NBUK, 256, 0, stream>>>(pairs, bbase, indptr, invdeg, esrc, M, E, NBUK);

    // --- bf16 convert + weight pack ---
    cvt_kernel<<<((M * 32) + 255) / 256, 256, 0, stream>>>(x, hbuf, M * 32);
    pack_kernel<<<(128 * 256 + 255) / 256, 256, 0, stream>>>(wself[0], wneigh[0], bpack0, 128);
    pack_kernel<<<(128 * 256 + 255) / 256, 256, 0, stream>>>(wself[1], wneigh[1], bpack1, 128);
    pack_kernel<<<(64 * 256 + 255) / 256, 256, 0, stream>>>(wself[2], wneigh[2], bpack2, 64);

    // --- layer 0 ---
    agg_kernel<false><<<(M + 3) / 4, 256, 0, stream>>>(hbuf, indptr, esrc, invdeg, nullptr, aggbuf, M);
    gemm2_kernel<4, true, false><<<GB, 256, 0, stream>>>(hbuf, aggbuf, bpack0, bias[0], nullptr,
                                                         preA, partials, M, T, GB * 2);
    hipMemsetAsync(colstat0, 0, 256 * 4, stream);
    bnred_kernel<<<32, 256, 0, stream>>>(partials, colstat0, GB);
    bnfin_kernel<<<1, 128, 0, stream>>>(colstat0, gamma[0], beta[0], 1.0f / (float)M);

    // --- layer 1 ---
    agg_kernel<true><<<(M + 3) / 4, 256, 0, stream>>>(preA, indptr, esrc, invdeg, colstat0, aggbuf, M);
    gemm2_kernel<4, true, true><<<GB, 256, 0, stream>>>(preA, aggbuf, bpack1, bias[1], colstat0,
                                                        preB, partials, M, T, GB * 2);
    hipMemsetAsync(colstat1, 0, 256 * 4, stream);
    bnred_kernel<<<32, 256, 0, stream>>>(partials, colstat1, GB);
    bnfin_kernel<<<1, 128, 0, stream>>>(colstat1, gamma[1], beta[1], 1.0f / (float)M);

    // --- layer 2 ---
    agg_kernel<true><<<(M + 3) / 4, 256, 0, stream>>>(preB, indptr, esrc, invdeg, colstat1, aggbuf, M);
    gemm2_kernel<2, false, true><<<GB, 256, 0, stream>>>(preB, aggbuf, bpack2, bias[2], colstat1,
                                                         preF, partials, M, T, GB * 2);
    lsm_kernel<<<(M + 3) / 4, 256, 0, stream>>>(preF, (float*)d_out, M);
}